// Round 1
// baseline (105.476 us; speedup 1.0000x reference)
//
#include <hip/hip_runtime.h>

#define KS   15
#define PAD  7
#define TILE 64
#define H_IN (TILE + KS - 1)   // 78
#define W_IN (TILE + KS - 1)   // 78

__global__ __launch_bounds__(256) void dcp_fused_kernel(
    const float* __restrict__ img, const float* __restrict__ weight,
    float* __restrict__ out, int H, int W)
{
    __shared__ float darkS[H_IN * W_IN];   // 78*78 = 6084 floats
    __shared__ float hsumS[H_IN * TILE];   // 78*64 = 4992 floats

    const int tid = threadIdx.x;
    const int tx0 = blockIdx.x * TILE;
    const int ty0 = blockIdx.y * TILE;
    const int b   = blockIdx.z;

    const long long plane = (long long)H * W;
    const float* base = img + (long long)b * 3 * plane;

    // Phase 1: dark channel (min over 3 channels) into LDS, zero outside image
    for (int i = tid; i < H_IN * W_IN; i += 256) {
        int r = i / W_IN, c = i - r * W_IN;
        int gy = ty0 + r - PAD;
        int gx = tx0 + c - PAD;
        float v = 0.0f;
        if (gy >= 0 && gy < H && gx >= 0 && gx < W) {
            long long off = (long long)gy * W + gx;
            float v0 = base[off];
            float v1 = base[off + plane];
            float v2 = base[off + 2 * plane];
            v = fminf(v0, fminf(v1, v2));
        }
        darkS[i] = v;
    }
    __syncthreads();

    // Phase 2: horizontal 15-tap sums: hsum[r][c] = sum_{k} darkS[r][c+k]
    for (int i = tid; i < H_IN * TILE; i += 256) {
        int r = i / TILE, c = i - r * TILE;
        const float* p = &darkS[r * W_IN + c];
        float s = 0.0f;
        #pragma unroll
        for (int k = 0; k < KS; ++k) s += p[k];
        hsumS[i] = s;
    }
    __syncthreads();

    const float scale = weight[0] * (1.0f / (KS * KS));

    // Phase 3: vertical 15-tap + scale, coalesced store
    for (int i = tid; i < TILE * TILE; i += 256) {
        int r = i / TILE, c = i - r * TILE;
        const float* p = &hsumS[r * TILE + c];
        float s = 0.0f;
        #pragma unroll
        for (int k = 0; k < KS; ++k) s += p[k * TILE];
        out[(long long)b * plane + (long long)(ty0 + r) * W + (tx0 + c)] = s * scale;
    }
}

extern "C" void kernel_launch(void* const* d_in, const int* in_sizes, int n_in,
                              void* d_out, int out_size, void* d_ws, size_t ws_size,
                              hipStream_t stream) {
    const float* img    = (const float*)d_in[0];
    const float* weight = (const float*)d_in[1];
    float* out = (float*)d_out;

    const int H = 1024, W = 1024, B = 16;
    dim3 grid(W / TILE, H / TILE, B);   // 16 x 16 x 16
    dim3 block(256);
    dcp_fused_kernel<<<grid, block, 0, stream>>>(img, weight, out, H, W);
}

// Round 2
// 90.334 us; speedup vs baseline: 1.1676x; 1.1676x over previous
//
#include <hip/hip_runtime.h>

#define KS   15
#define PAD  7
#define TILE 64
#define HI   (TILE + KS - 1)   // 78
#define WI   (TILE + KS - 1)   // 78
#define LDW  81                // padded LDS row stride (odd -> bank-conflict-free phases)

__global__ __launch_bounds__(256, 5) void dcp_kernel(
    const float* __restrict__ img, const float* __restrict__ weight,
    float* __restrict__ out, int H, int W)
{
    __shared__ float S[HI * LDW];   // 78*81*4 = 25272 B

    const int tid = threadIdx.x;
    const int tx0 = blockIdx.x * TILE;
    const int ty0 = blockIdx.y * TILE;
    const int b   = blockIdx.z;
    const long long plane = (long long)H * W;
    const float* base = img + (long long)b * 3 * plane;

    // ---- Phase 1: dark channel (min over 3 channels) into S, zero outside ----
    for (int i = tid; i < HI * WI; i += 256) {
        int r = i / WI, c = i - r * WI;
        int gy = ty0 + r - PAD, gx = tx0 + c - PAD;
        float v = 0.0f;
        if ((unsigned)gy < (unsigned)H && (unsigned)gx < (unsigned)W) {
            long long off = (long long)gy * W + gx;
            v = fminf(base[off], fminf(base[off + plane], base[off + 2 * plane]));
        }
        S[r * LDW + c] = v;
    }
    __syncthreads();

    float buf[30];

    // ---- Phase 2: vertical 15-tap sliding sums, IN PLACE in S ----
    // item = (column c in [0,78), y-segment s in [0,4)): 16 outputs, 30 inputs.
    // Round A: c = tid>>2 in [0,64)  (all 256 threads)
    {
        const int cA = tid >> 2, sA = tid & 3;
        const int bA = sA * 16 * LDW + cA;
        #pragma unroll
        for (int k = 0; k < 30; ++k) buf[k] = S[bA + k * LDW];
        __syncthreads();
        float run = 0.0f;
        #pragma unroll
        for (int k = 0; k < 14; ++k) run += buf[k];
        #pragma unroll
        for (int j = 0; j < 16; ++j) {
            run += buf[j + 14];
            S[bA + j * LDW] = run;   // writes cols 0..63 only
            run -= buf[j];
        }
    }
    // Round B: c = 64 + (tid>>2), tid < 56 (cols 64..77; disjoint from round-A writes)
    {
        const int cB = 64 + (tid >> 2), sB = tid & 3;
        const int bB = sB * 16 * LDW + cB;
        if (tid < 56) {
            #pragma unroll
            for (int k = 0; k < 30; ++k) buf[k] = S[bB + k * LDW];
        }
        __syncthreads();
        if (tid < 56) {
            float run = 0.0f;
            #pragma unroll
            for (int k = 0; k < 14; ++k) run += buf[k];
            #pragma unroll
            for (int j = 0; j < 16; ++j) {
                run += buf[j + 14];
                S[bB + j * LDW] = run;
                run -= buf[j];
            }
        }
        __syncthreads();
    }

    // ---- Phase 3: horizontal 15-tap sliding sums + scale, float4 stores ----
    const float scale = weight[0] * (1.0f / (KS * KS));
    {
        const int r = tid >> 2, s = tid & 3;     // row in [0,64), x-segment of 16
        const int bp = r * LDW + s * 16;
        #pragma unroll
        for (int k = 0; k < 30; ++k) buf[k] = S[bp + k];
        float o[16];
        float run = 0.0f;
        #pragma unroll
        for (int k = 0; k < 14; ++k) run += buf[k];
        #pragma unroll
        for (int j = 0; j < 16; ++j) {
            run += buf[j + 14];
            o[j] = run * scale;
            run -= buf[j];
        }
        float* dst = out + (long long)b * plane + (long long)(ty0 + r) * W + (tx0 + s * 16);
        #pragma unroll
        for (int q = 0; q < 4; ++q) {
            *reinterpret_cast<float4*>(dst + 4 * q) =
                make_float4(o[4 * q], o[4 * q + 1], o[4 * q + 2], o[4 * q + 3]);
        }
    }
}

extern "C" void kernel_launch(void* const* d_in, const int* in_sizes, int n_in,
                              void* d_out, int out_size, void* d_ws, size_t ws_size,
                              hipStream_t stream) {
    const float* img    = (const float*)d_in[0];
    const float* weight = (const float*)d_in[1];
    float* out = (float*)d_out;

    const int H = 1024, W = 1024, B = 16;
    dim3 grid(W / TILE, H / TILE, B);   // 16 x 16 x 16
    dim3 block(256);
    dcp_kernel<<<grid, block, 0, stream>>>(img, weight, out, H, W);
}

// Round 3
// 58.834 us; speedup vs baseline: 1.7928x; 1.5354x over previous
//
#include <hip/hip_runtime.h>

#define KS   15
#define PAD  7
#define TILE 64
#define HI   (TILE + KS - 1)   // 78 rows in LDS
#define LDW  84                // LDS row stride (floats): %32==20 -> b128 conflict-free; %4==0 -> 16B aligned
#define NQ   20                // float4s per loaded row (80-float window [tx0-8, tx0+72))

__global__ __launch_bounds__(256, 6) void dcp_kernel(
    const float* __restrict__ img, const float* __restrict__ weight,
    float* __restrict__ out)
{
    __shared__ float S[HI * LDW];   // 78*84*4 = 26208 B -> 6 blocks/CU

    const int tid  = threadIdx.x;
    const int wave = tid >> 6;
    const int lane = tid & 63;

    // XCD-chunked swizzle: 4096 blocks, 8 XCDs -> each XCD gets 512 contiguous
    // logical tiles (= 2 whole images, row-major) for y-halo L2 reuse.
    const int bid = blockIdx.x;
    const int swz = (bid & 7) * 512 + (bid >> 3);
    const int b   = swz >> 8;
    const int ty0 = ((swz >> 4) & 15) * TILE;
    const int tx0 = (swz & 15) * TILE;

    const int H = 1024, W = 1024;
    const long long plane = (long long)H * W;
    const float* base = img + (long long)b * 3 * plane;
    const float scale = weight[0] * (1.0f / (KS * KS));

    // ---- Phase 1: dark channel via float4 loads, b128 LDS writes ----
    for (int it = tid; it < HI * NQ; it += 256) {
        const int r  = it / NQ;
        const int c4 = it - r * NQ;
        const int gy = ty0 + r - PAD;
        const int gx = tx0 - 8 + 4 * c4;     // quad-aligned; never straddles image edge
        float4 v = make_float4(0.f, 0.f, 0.f, 0.f);
        if ((unsigned)gy < (unsigned)H && (unsigned)gx <= (unsigned)(W - 4)) {
            const long long off = (long long)gy * W + gx;
            const float4 a0 = *(const float4*)(base + off);
            const float4 a1 = *(const float4*)(base + off + plane);
            const float4 a2 = *(const float4*)(base + off + 2 * plane);
            v.x = fminf(a0.x, fminf(a1.x, a2.x));
            v.y = fminf(a0.y, fminf(a1.y, a2.y));
            v.z = fminf(a0.z, fminf(a1.z, a2.z));
            v.w = fminf(a0.w, fminf(a1.w, a2.w));
        }
        *(float4*)(&S[r * LDW + 4 * c4]) = v;
    }
    __syncthreads();

    float buf[32] __attribute__((aligned(16)));

    // ---- Phase 2: vertical 15-tap sliding sums, in place ----
    // Round A: wave = y-segment (16 out rows), lane = column 0..63
    {
        const int rb = wave * 16;
        #pragma unroll
        for (int k = 0; k < 30; ++k) buf[k] = S[(rb + k) * LDW + lane];
        __syncthreads();
        float run = 0.f;
        #pragma unroll
        for (int k = 0; k < 14; ++k) run += buf[k];
        #pragma unroll
        for (int j = 0; j < 16; ++j) {
            run += buf[j + 14];
            S[(rb + j) * LDW + lane] = run;   // cols 0..63
            run -= buf[j];
        }
    }
    // Round B: columns 64..79, lanes 0..15 of each wave (disjoint from A writes)
    {
        const int rb = wave * 16;
        const int c  = 64 + lane;
        if (lane < 16) {
            #pragma unroll
            for (int k = 0; k < 30; ++k) buf[k] = S[(rb + k) * LDW + c];
        }
        __syncthreads();
        if (lane < 16) {
            float run = 0.f;
            #pragma unroll
            for (int k = 0; k < 14; ++k) run += buf[k];
            #pragma unroll
            for (int j = 0; j < 16; ++j) {
                run += buf[j + 14];
                S[(rb + j) * LDW + c] = run;
                run -= buf[j];
            }
        }
        __syncthreads();
    }

    // ---- Phase 3: horizontal 15-tap sliding + scale; b128 LDS reads, float4 stores ----
    {
        const int r = lane;                    // output row 0..63
        const int s = wave;                    // x-segment of 16
        const int bp = r * LDW + s * 16;       // 16B-aligned
        #pragma unroll
        for (int q = 0; q < 8; ++q)
            *(float4*)(&buf[4 * q]) = *(const float4*)(&S[bp + 4 * q]);
        // out[x] for x = s*16+j needs vsum S-cols [x+1 .. x+15] (S col = x+8 window)
        float o[16];
        float run = 0.f;
        #pragma unroll
        for (int k = 1; k <= 14; ++k) run += buf[k];
        #pragma unroll
        for (int j = 0; j < 16; ++j) {
            run += buf[j + 15];
            o[j] = run * scale;
            run -= buf[j + 1];
        }
        float* dst = out + (long long)b * plane + (long long)(ty0 + r) * W + (tx0 + s * 16);
        #pragma unroll
        for (int q = 0; q < 4; ++q)
            *(float4*)(dst + 4 * q) =
                make_float4(o[4 * q], o[4 * q + 1], o[4 * q + 2], o[4 * q + 3]);
    }
}

extern "C" void kernel_launch(void* const* d_in, const int* in_sizes, int n_in,
                              void* d_out, int out_size, void* d_ws, size_t ws_size,
                              hipStream_t stream) {
    const float* img    = (const float*)d_in[0];
    const float* weight = (const float*)d_in[1];
    float* out = (float*)d_out;

    dim3 grid(4096);     // 16 tiles x * 16 tiles y * 16 batch
    dim3 block(256);
    dcp_kernel<<<grid, block, 0, stream>>>(img, weight, out);
}

// Round 4
// 53.333 us; speedup vs baseline: 1.9777x; 1.1031x over previous
//
#include <hip/hip_runtime.h>

#define KS   15
#define PAD  7
#define TILE 64
#define HI   (TILE + KS - 1)   // 78 rows in LDS
#define LDW  84                // LDS row stride (floats): LDW/4=21 odd mult of 4 -> minimal b128 conflicts
#define NQ   20                // float4s per loaded row (80-float window [tx0-8, tx0+72))
#define NIT  (HI * NQ)         // 1560 quad-items per tile
#define STR2 68                // output-staging stride (68/4=17 odd -> conflict-minimal)

__global__ __launch_bounds__(256, 6) void dcp_kernel(
    const float* __restrict__ img, const float* __restrict__ weight,
    float* __restrict__ out)
{
    __shared__ float S[HI * LDW];   // 78*84*4 = 26208 B -> 6 blocks/CU

    const int tid  = threadIdx.x;
    const int wave = tid >> 6;
    const int lane = tid & 63;

    // XCD-chunked swizzle: each XCD gets 512 contiguous logical tiles (2 images).
    const int bid = blockIdx.x;
    const int swz = (bid & 7) * 512 + (bid >> 3);
    const int b   = swz >> 8;
    const int ty0 = ((swz >> 4) & 15) * TILE;
    const int tx0 = (swz & 15) * TILE;

    const int H = 1024, W = 1024;
    const long long plane = (long long)H * W;
    const float* base = img + (long long)b * 3 * plane;
    const float scale = weight[0] * (1.0f / (KS * KS));

    // ---- Phase 1: dark channel, software-pipelined float4 loads (depth 2) ----
    auto load3 = [&](int it, float4* c) {
        int r  = it / NQ;
        int c4 = it - r * NQ;
        int gy = ty0 + r - PAD;
        int gx = tx0 - 8 + 4 * c4;          // quad-aligned, never straddles edge
        if ((unsigned)gy < (unsigned)H && (unsigned)gx <= (unsigned)(W - 4)) {
            long long off = (long long)gy * W + gx;
            c[0] = *(const float4*)(base + off);
            c[1] = *(const float4*)(base + off + plane);
            c[2] = *(const float4*)(base + off + 2 * plane);
        } else {
            c[0] = c[1] = c[2] = make_float4(0.f, 0.f, 0.f, 0.f);
        }
    };
    auto write_min = [&](int it, const float4* c) {
        int r  = it / NQ;
        int c4 = it - r * NQ;
        float4 v;
        v.x = fminf(c[0].x, fminf(c[1].x, c[2].x));
        v.y = fminf(c[0].y, fminf(c[1].y, c[2].y));
        v.z = fminf(c[0].z, fminf(c[1].z, c[2].z));
        v.w = fminf(c[0].w, fminf(c[1].w, c[2].w));
        *(float4*)(&S[r * LDW + 4 * c4]) = v;
    };

    {
        float4 c0[3], c1[3];
        load3(tid, c0);                      // items 0..1535: 6 rounds, all threads
        #pragma unroll
        for (int k = 0; k < 5; ++k) {
            load3(tid + 256 * (k + 1), c1);  // issue next round's loads first
            write_min(tid + 256 * k, c0);    // then wait + write current
            c0[0] = c1[0]; c0[1] = c1[1]; c0[2] = c1[2];
        }
        write_min(tid + 256 * 5, c0);
        if (tid < NIT - 1536) {              // tail items 1536..1559
            load3(1536 + tid, c0);
            write_min(1536 + tid, c0);
        }
    }
    __syncthreads();

    float buf[32] __attribute__((aligned(16)));

    // ---- Phase 2: vertical 15-tap sliding sums, in place ----
    // Round A: wave = y-segment (16 out rows), lane = column 0..63
    {
        const int rb = wave * 16;
        #pragma unroll
        for (int k = 0; k < 30; ++k) buf[k] = S[(rb + k) * LDW + lane];
        __syncthreads();
        float run = 0.f;
        #pragma unroll
        for (int k = 0; k < 14; ++k) run += buf[k];
        #pragma unroll
        for (int j = 0; j < 16; ++j) {
            run += buf[j + 14];
            S[(rb + j) * LDW + lane] = run;   // cols 0..63
            run -= buf[j];
        }
    }
    // Round B: columns 64..79, lanes 0..15 of each wave (disjoint from A writes)
    {
        const int rb = wave * 16;
        const int c  = 64 + lane;
        if (lane < 16) {
            #pragma unroll
            for (int k = 0; k < 30; ++k) buf[k] = S[(rb + k) * LDW + c];
        }
        __syncthreads();
        if (lane < 16) {
            float run = 0.f;
            #pragma unroll
            for (int k = 0; k < 14; ++k) run += buf[k];
            #pragma unroll
            for (int j = 0; j < 16; ++j) {
                run += buf[j + 14];
                S[(rb + j) * LDW + c] = run;
                run -= buf[j];
            }
        }
        __syncthreads();
    }

    // ---- Phase 3: horizontal 15-tap sliding + scale ----
    {
        const int r = lane;                    // output row 0..63
        const int s = wave;                    // x-segment of 16
        const int bp = r * LDW + s * 16;       // 16B-aligned
        #pragma unroll
        for (int q = 0; q < 8; ++q)
            *(float4*)(&buf[4 * q]) = *(const float4*)(&S[bp + 4 * q]);
        float o[16];
        float run = 0.f;
        #pragma unroll
        for (int k = 1; k <= 14; ++k) run += buf[k];
        #pragma unroll
        for (int j = 0; j < 16; ++j) {
            run += buf[j + 15];
            o[j] = run * scale;
            run -= buf[j + 1];
        }
        __syncthreads();                       // all P3 S-reads done
        // stage outputs to LDS for coalesced global stores
        #pragma unroll
        for (int q = 0; q < 4; ++q)
            *(float4*)(&S[r * STR2 + s * 16 + 4 * q]) =
                make_float4(o[4 * q], o[4 * q + 1], o[4 * q + 2], o[4 * q + 3]);
    }
    __syncthreads();

    // ---- Phase 4: coalesced copy-out (consecutive lanes -> consecutive quads) ----
    {
        float* obase = out + (long long)b * plane + (long long)ty0 * W + tx0;
        #pragma unroll
        for (int k = 0; k < 4; ++k) {
            const int qi  = tid + 256 * k;     // 1024 quads total
            const int row = qi >> 4;
            const int qc  = qi & 15;
            float4 v = *(const float4*)(&S[row * STR2 + 4 * qc]);
            *(float4*)(obase + (long long)row * W + 4 * qc) = v;
        }
    }
}

extern "C" void kernel_launch(void* const* d_in, const int* in_sizes, int n_in,
                              void* d_out, int out_size, void* d_ws, size_t ws_size,
                              hipStream_t stream) {
    const float* img    = (const float*)d_in[0];
    const float* weight = (const float*)d_in[1];
    float* out = (float*)d_out;

    dim3 grid(4096);     // 16 tiles x * 16 tiles y * 16 batch
    dim3 block(256);
    dcp_kernel<<<grid, block, 0, stream>>>(img, weight, out);
}